// Round 1
// baseline (541.482 us; speedup 1.0000x reference)
//
#include <hip/hip_runtime.h>

#define B 8
#define N 512
#define D 256
#define DH 64
#define NEG_INF (-1.0e9f)
#define ROWS 8   // x-rows per qkv block

// ---------------- QKV projection ----------------
// grid: B*N/ROWS blocks, 192 threads (3 waves: Q, K, V)
__global__ __launch_bounds__(192) void qkv_kernel(
    const float* __restrict__ x, const int* __restrict__ mask,
    const float* __restrict__ Wq, const float* __restrict__ bq,
    const float* __restrict__ Wk, const float* __restrict__ bk,
    const float* __restrict__ Wv, const float* __restrict__ bv,
    float* __restrict__ Q, float* __restrict__ K, float* __restrict__ V)
{
    __shared__ float xs[ROWS * D];
    const int tid  = threadIdx.x;
    const int row0 = blockIdx.x * ROWS;

    // stage ROWS x-rows (contiguous) into LDS with float4 loads
    const float4* x4  = (const float4*)(x + (size_t)row0 * D);
    float4*       xs4 = (float4*)xs;
    for (int i = tid; i < ROWS * D / 4; i += 192) xs4[i] = x4[i];
    __syncthreads();

    const int which = tid >> 6;   // wave-uniform: 0=Q,1=K,2=V
    const int o     = tid & 63;
    const float* W    = (which == 0) ? Wq : (which == 1) ? Wk : Wv;
    const float* bias = (which == 0) ? bq : (which == 1) ? bk : bv;
    float*       Out  = (which == 0) ? Q  : (which == 1) ? K  : V;

    float acc[ROWS];
    const float bo = bias[o];
#pragma unroll
    for (int r = 0; r < ROWS; ++r) acc[r] = bo;

    for (int k = 0; k < D; ++k) {
        const float w = W[k * DH + o];     // coalesced per wave, L2-hot
#pragma unroll
        for (int r = 0; r < ROWS; ++r)
            acc[r] += xs[r * D + k] * w;   // LDS broadcast (free)
    }

#pragma unroll
    for (int r = 0; r < ROWS; ++r) {
        const int row = row0 + r;
        const float m = (float)mask[row];
        Out[(size_t)row * DH + o] = acc[r] * m;
    }
}

// ---------------- attention: one block per (b, i) ----------------
// 256 threads: each owns scores j=tid and j=tid+256
__global__ __launch_bounds__(256) void attn_kernel(
    const float* __restrict__ Q, const float* __restrict__ K,
    const float* __restrict__ V, const int* __restrict__ mask,
    float* __restrict__ out)
{
    const int b   = blockIdx.x >> 9;      // / N
    const int i   = blockIdx.x & (N - 1); // % N
    const int tid = threadIdx.x;
    const int w   = tid >> 6;             // wave id 0..3
    const int o   = tid & 63;

    __shared__ float qs[DH];
    __shared__ float sc[N];               // exp weights
    __shared__ float redm[4], reds[4];
    __shared__ float pv[4][DH];

    const int rowi = b * N + i;
    if (mask[rowi] == 0) {
        if (tid < DH) out[(size_t)rowi * DH + tid] = 0.0f;
        return;
    }

    if (tid < DH) qs[tid] = Q[(size_t)rowi * DH + tid];
    __syncthreads();

    // ---- scores ----
    float s[2];
    const float4* q4 = (const float4*)qs;
#pragma unroll
    for (int jj = 0; jj < 2; ++jj) {
        const int j = tid + jj * 256;
        const float4* k4 = (const float4*)(K + (size_t)(b * N + j) * DH);
        float acc = 0.0f;
#pragma unroll
        for (int kk = 0; kk < DH / 4; ++kk) {
            const float4 kv = k4[kk];
            const float4 qv = q4[kk];
            acc += qv.x * kv.x + qv.y * kv.y + qv.z * kv.z + qv.w * kv.w;
        }
        s[jj] = mask[b * N + j] ? acc * 0.125f : NEG_INF;  // /sqrt(64)
    }

    // ---- block max ----
    float m = fmaxf(s[0], s[1]);
#pragma unroll
    for (int off = 32; off > 0; off >>= 1)
        m = fmaxf(m, __shfl_xor(m, off));
    if (o == 0) redm[w] = m;
    __syncthreads();
    const float M = fmaxf(fmaxf(redm[0], redm[1]), fmaxf(redm[2], redm[3]));

    // ---- exp + block sum ----
    const float p0 = __expf(s[0] - M);
    const float p1 = __expf(s[1] - M);
    sc[tid]       = p0;
    sc[tid + 256] = p1;
    float sum = p0 + p1;
#pragma unroll
    for (int off = 32; off > 0; off >>= 1)
        sum += __shfl_xor(sum, off);
    if (o == 0) reds[w] = sum;
    __syncthreads();
    const float invSum = 1.0f / (reds[0] + reds[1] + reds[2] + reds[3]);

    // ---- PV: wave w handles j in [w*128, w*128+128), column o ----
    float partial = 0.0f;
    const int j0 = w * 128;
    for (int j = j0; j < j0 + 128; ++j)
        partial += sc[j] * V[(size_t)(b * N + j) * DH + o];  // coalesced V
    pv[w][o] = partial;
    __syncthreads();

    if (tid < DH) {
        const float res = (pv[0][tid] + pv[1][tid] + pv[2][tid] + pv[3][tid]) * invSum;
        out[(size_t)rowi * DH + tid] = res;
    }
}

extern "C" void kernel_launch(void* const* d_in, const int* in_sizes, int n_in,
                              void* d_out, int out_size, void* d_ws, size_t ws_size,
                              hipStream_t stream)
{
    const float* x    = (const float*)d_in[0];
    const float* e    = (const float*)d_in[1];
    const int*   mask = (const int*)  d_in[2];
    const float* Wq   = (const float*)d_in[3];
    const float* bq   = (const float*)d_in[4];
    const float* Wk   = (const float*)d_in[5];
    const float* bk   = (const float*)d_in[6];
    const float* Wv   = (const float*)d_in[7];
    const float* bv   = (const float*)d_in[8];

    float* out  = (float*)d_out;                    // (B,N,DH) = 262144 floats
    float* eout = out + (size_t)B * N * DH;         // e passthrough chunk

    float* Q = (float*)d_ws;
    float* K = Q + (size_t)B * N * DH;
    float* V = K + (size_t)B * N * DH;

    // e passthrough: 256 MB D2D copy (graph-capture safe)
    hipMemcpyAsync(eout, e, (size_t)in_sizes[1] * sizeof(float),
                   hipMemcpyDeviceToDevice, stream);

    qkv_kernel<<<B * N / ROWS, 192, 0, stream>>>(x, mask, Wq, bq, Wk, bk, Wv, bv, Q, K, V);
    attn_kernel<<<B * N, 256, 0, stream>>>(Q, K, V, mask, out);
}

// Round 2
// 537.990 us; speedup vs baseline: 1.0065x; 1.0065x over previous
//
#include <hip/hip_runtime.h>

#define B 8
#define N 512
#define D 256
#define DH 64
#define NEG_INF (-1.0e9f)
#define ROWS 8            // x-rows per qkv block

#define ATTN_BLOCKS (B * N)          // 4096
#define COPY_BLOCKS 8192
#define COPY_F4     (B * (size_t)N * N * 32 / 4)   // 16,777,216 float4
#define COPY_ITERS  (COPY_F4 / ((size_t)COPY_BLOCKS * 256))  // 8

// ---------------- QKV projection ----------------
// grid: B*N/ROWS blocks, 192 threads (3 waves: Q, K, V)
__global__ __launch_bounds__(192) void qkv_kernel(
    const float* __restrict__ x, const int* __restrict__ mask,
    const float* __restrict__ Wq, const float* __restrict__ bq,
    const float* __restrict__ Wk, const float* __restrict__ bk,
    const float* __restrict__ Wv, const float* __restrict__ bv,
    float* __restrict__ Q, float* __restrict__ K, float* __restrict__ V)
{
    __shared__ float xs[ROWS * D];
    const int tid  = threadIdx.x;
    const int row0 = blockIdx.x * ROWS;

    const float4* x4  = (const float4*)(x + (size_t)row0 * D);
    float4*       xs4 = (float4*)xs;
    for (int i = tid; i < ROWS * D / 4; i += 192) xs4[i] = x4[i];
    __syncthreads();

    const int which = tid >> 6;   // wave-uniform: 0=Q,1=K,2=V
    const int o     = tid & 63;
    const float* W    = (which == 0) ? Wq : (which == 1) ? Wk : Wv;
    const float* bias = (which == 0) ? bq : (which == 1) ? bk : bv;
    float*       Out  = (which == 0) ? Q  : (which == 1) ? K  : V;

    float acc[ROWS];
    const float bo = bias[o];
#pragma unroll
    for (int r = 0; r < ROWS; ++r) acc[r] = bo;

    for (int k = 0; k < D; ++k) {
        const float w = W[k * DH + o];     // coalesced per wave, L2-hot
#pragma unroll
        for (int r = 0; r < ROWS; ++r)
            acc[r] += xs[r * D + k] * w;   // LDS broadcast
    }

#pragma unroll
    for (int r = 0; r < ROWS; ++r) {
        const int row = row0 + r;
        const float m = (float)mask[row];
        Out[(size_t)row * DH + o] = acc[r] * m;
    }
}

// ---------------- fused: attention (blocks 0..4095) + e-copy (rest) ----------
__global__ __launch_bounds__(256) void fused_attn_copy(
    const float* __restrict__ Q, const float* __restrict__ K,
    const float* __restrict__ V, const int* __restrict__ mask,
    const float4* __restrict__ e4, float4* __restrict__ eout4,
    float* __restrict__ out)
{
    const int tid = threadIdx.x;

    if (blockIdx.x >= ATTN_BLOCKS) {
        // ---- e passthrough: float4 grid-strided copy at HBM rate ----
        const size_t stride = (size_t)COPY_BLOCKS * 256;
        size_t idx = (size_t)(blockIdx.x - ATTN_BLOCKS) * 256 + tid;
#pragma unroll
        for (int r = 0; r < (int)COPY_ITERS; ++r) {
            eout4[idx] = e4[idx];
            idx += stride;
        }
        return;
    }

    // ---- attention: one block per (b, i) ----
    const int b = blockIdx.x >> 9;       // / N
    const int i = blockIdx.x & (N - 1);  // % N
    const int w = tid >> 6;              // wave id 0..3
    const int o = tid & 63;

    __shared__ float qs[DH];
    __shared__ float sc[N];
    __shared__ float redm[4], reds[4];
    __shared__ float pv[4][DH];

    const int rowi = b * N + i;
    if (mask[rowi] == 0) {               // block-uniform branch
        if (tid < DH) out[(size_t)rowi * DH + tid] = 0.0f;
        return;
    }

    if (tid < DH) qs[tid] = Q[(size_t)rowi * DH + tid];
    __syncthreads();

    // ---- scores ----
    float s[2];
    const float4* q4 = (const float4*)qs;
#pragma unroll
    for (int jj = 0; jj < 2; ++jj) {
        const int j = tid + jj * 256;
        const float4* k4 = (const float4*)(K + (size_t)(b * N + j) * DH);
        float acc = 0.0f;
#pragma unroll
        for (int kk = 0; kk < DH / 4; ++kk) {
            const float4 kv = k4[kk];
            const float4 qv = q4[kk];
            acc += qv.x * kv.x + qv.y * kv.y + qv.z * kv.z + qv.w * kv.w;
        }
        s[jj] = mask[b * N + j] ? acc * 0.125f : NEG_INF;  // /sqrt(64)
    }

    // ---- block max ----
    float m = fmaxf(s[0], s[1]);
#pragma unroll
    for (int off = 32; off > 0; off >>= 1)
        m = fmaxf(m, __shfl_xor(m, off));
    if (o == 0) redm[w] = m;
    __syncthreads();
    const float M = fmaxf(fmaxf(redm[0], redm[1]), fmaxf(redm[2], redm[3]));

    // ---- exp + block sum ----
    const float p0 = __expf(s[0] - M);
    const float p1 = __expf(s[1] - M);
    sc[tid]       = p0;
    sc[tid + 256] = p1;
    float sum = p0 + p1;
#pragma unroll
    for (int off = 32; off > 0; off >>= 1)
        sum += __shfl_xor(sum, off);
    if (o == 0) reds[w] = sum;
    __syncthreads();
    const float invSum = 1.0f / (reds[0] + reds[1] + reds[2] + reds[3]);

    // ---- PV: wave w handles j in [w*128, w*128+128), column o ----
    float partial = 0.0f;
    const int j0 = w * 128;
    for (int j = j0; j < j0 + 128; ++j)
        partial += sc[j] * V[(size_t)(b * N + j) * DH + o];
    pv[w][o] = partial;
    __syncthreads();

    if (tid < DH) {
        const float res = (pv[0][tid] + pv[1][tid] + pv[2][tid] + pv[3][tid]) * invSum;
        out[(size_t)rowi * DH + tid] = res;
    }
}

extern "C" void kernel_launch(void* const* d_in, const int* in_sizes, int n_in,
                              void* d_out, int out_size, void* d_ws, size_t ws_size,
                              hipStream_t stream)
{
    const float* x    = (const float*)d_in[0];
    const float* e    = (const float*)d_in[1];
    const int*   mask = (const int*)  d_in[2];
    const float* Wq   = (const float*)d_in[3];
    const float* bq   = (const float*)d_in[4];
    const float* Wk   = (const float*)d_in[5];
    const float* bk   = (const float*)d_in[6];
    const float* Wv   = (const float*)d_in[7];
    const float* bv   = (const float*)d_in[8];

    float* out  = (float*)d_out;                    // (B,N,DH) first
    float* eout = out + (size_t)B * N * DH;         // then e passthrough

    float* Q = (float*)d_ws;
    float* K = Q + (size_t)B * N * DH;
    float* V = K + (size_t)B * N * DH;

    qkv_kernel<<<B * N / ROWS, 192, 0, stream>>>(x, mask, Wq, bq, Wk, bk, Wv, bv, Q, K, V);
    fused_attn_copy<<<ATTN_BLOCKS + COPY_BLOCKS, 256, 0, stream>>>(
        Q, K, V, mask, (const float4*)e, (float4*)eout, out);
}